// Round 1
// baseline (84.565 us; speedup 1.0000x reference)
//
#include <hip/hip_runtime.h>
#include <stdint.h>
#include <math.h>

// ---------------------------------------------------------------------------
// SparseExplorerRouting, round 4.
//
// Carried facts (R1-R3 PASSED, absmax 0):
//   * jax_threefry_partitionable=True counter scheme; key(42) -> (0,42);
//     walk (v,w) = split child v*5+w; per-step children ctr (0,{0,1,2}).
//   * output int32 {flags[1024], sum_aborts, sum_restarts}.
//   * f64 analog math proxy for the f32 reference passes with margin.
//   * E-table argmax(E/w) trick, w=-log(u); minE<e^0.5 == min_sim<0.1.
//
// Round 4 changes (all bit-identical numerics):
//   * band+rowsq FUSED: one 512-thread block stages 32 rows (16 centers +
//     16 halo) in 128 KB LDS, computes sumsq during staging (same per-lane
//     order + same butterfly as old rowsq -> bit-identical), then the 16
//     forward band dots per center from LDS (same accumulation order ->
//     bit-identical E). Kills the 33.5 MB rowsq re-read of H and cuts band
//     global traffic 557 MB -> 67 MB (was L2-BW bound at ~34.5 TB/s).
//   * walk argmax: max-butterfly (fmax propagates inputs exactly) +
//     ballot(f==m) + ffsll  == old smallest-index tie-break, ~40% fewer
//     reduce instrs.
//   * kr threefry chain deferred into the (rare) restart branch.
// ---------------------------------------------------------------------------

#define HID        1024
#define NUM_WALKS  5
#define WALK_LEN   8
#define HALF_WIN   16
#define E_THRESH   1.6487212707001282   // exp(0.5) = exp(5 * BIRTH_DEATH_EPS)

#define CENTERS    16                   // centers per band block
#define SROWS      32                   // staged rows = CENTERS + 16 halo

__device__ __forceinline__ void tf2x32(uint32_t k0, uint32_t k1,
                                       uint32_t& x0, uint32_t& x1) {
  uint32_t ks2 = k0 ^ k1 ^ 0x1BD11BDAu;
  x0 += k0; x1 += k1;
#define TFR(r) { x0 += x1; x1 = (x1 << (r)) | (x1 >> (32 - (r))); x1 ^= x0; }
  TFR(13) TFR(15) TFR(26) TFR(6)
  x0 += k1;  x1 += ks2 + 1u;
  TFR(17) TFR(29) TFR(16) TFR(24)
  x0 += ks2; x1 += k0 + 2u;
  TFR(13) TFR(15) TFR(26) TFR(6)
  x0 += k0;  x1 += k1 + 3u;
  TFR(17) TFR(29) TFR(16) TFR(24)
  x0 += k1;  x1 += ks2 + 4u;
  TFR(13) TFR(15) TFR(26) TFR(6)
  x0 += ks2; x1 += k0 + 5u;
#undef TFR
}

__device__ __forceinline__ uint32_t tf_fold(uint32_t k0, uint32_t k1,
                                            uint32_t c0, uint32_t c1) {
  tf2x32(k0, k1, c0, c1);
  return c0 ^ c1;
}

// ---- fused band + rowsq + d_out zeroing ------------------------------------
// Block = 512 threads (8 waves) = 16 centers. Stage rows [i0, i0+32) as f32
// in LDS; compute per-row sumsq during staging (bit-identical order to the
// old rowsq kernel); then 16 forward dots per center from LDS (bit-identical
// order to the old band kernel). E[i][16+d] = E[i+d][16-d] = exp(5*sim).
__global__ __launch_bounds__(512) void band_fused_kernel(
    const float* __restrict__ H, double* __restrict__ sumsq,
    double* __restrict__ E, int* __restrict__ out, int out_n, int seq_len) {
  __shared__ __align__(16) float  tile[SROWS][HID];   // 128 KB
  __shared__ double ssq[SROWS];

  if (blockIdx.x == 0) {                 // fold d_out zeroing in (own dispatch
    for (int t = threadIdx.x; t < out_n; t += 512) out[t] = 0;   // ordering
  }                                      // guarantees walk sees zeros)

  int wg = blockIdx.x;
  {
    const int nwg = gridDim.x;           // bijective XCD swizzle (nwg%8==0)
    if ((nwg & 7) == 0) wg = (wg & 7) * (nwg >> 3) + (wg >> 3);
  }
  const int wid  = (int)(threadIdx.x >> 6);   // 0..7
  const int lane = (int)(threadIdx.x & 63);
  const int i0   = wg * CENTERS;
  const float4* __restrict__ H4 = (const float4*)H;

  // ---- stage 4 rows per wave + sumsq (same order as old rowsq) ----
#pragma unroll
  for (int rr = 0; rr < 4; ++rr) {
    const int local = wid * 4 + rr;      // wave-uniform
    const int row   = i0 + local;
    if (row < seq_len) {
      const float4* src = H4 + ((size_t)row << 8);
      float4* dst = (float4*)&tile[local][0];
      double acc = 0.0;
#pragma unroll
      for (int k = 0; k < 4; ++k) {
        float4 x = src[lane + (k << 6)];
        dst[lane + (k << 6)] = x;
        acc += (double)x.x * x.x + (double)x.y * x.y
             + (double)x.z * x.z + (double)x.w * x.w;
      }
#pragma unroll
      for (int off = 32; off; off >>= 1) acc += __shfl_xor(acc, off);
      if (lane == 0) {
        ssq[local] = acc;
        if (local < CENTERS) sumsq[row] = acc;   // each row owned by 1 block
      }
    }
  }
  __syncthreads();

  // ---- 2 centers per wave, 16 forward dots each, from LDS ----
#pragma unroll
  for (int cc = 0; cc < 2; ++cc) {
    const int cl = wid * 2 + cc;         // 0..15, wave-uniform
    const int i  = i0 + cl;
    if (i >= seq_len) continue;

    double a[16];
    {
      const float4* rc = (const float4*)&tile[cl][0];
#pragma unroll
      for (int k = 0; k < 4; ++k) {
        float4 x = rc[lane + (k << 6)];
        a[4*k+0] = x.x; a[4*k+1] = x.y; a[4*k+2] = x.z; a[4*k+3] = x.w;
      }
    }
    const double ni = sqrt(ssq[cl]) + 1e-8;

    double p[16];
#pragma unroll
    for (int d = 0; d < 16; ++d) p[d] = 0.0;
    const int dmax = (seq_len - 1 - i < 16) ? (seq_len - 1 - i) : 16;
    for (int d = 1; d <= dmax; ++d) {
      const float4* rb = (const float4*)&tile[cl + d][0];
#pragma unroll
      for (int k = 0; k < 4; ++k) {
        float4 x = rb[lane + (k << 6)];
        p[d-1] += a[4*k+0] * (double)x.x + a[4*k+1] * (double)x.y
                + a[4*k+2] * (double)x.z + a[4*k+3] * (double)x.w;
      }
    }

    // multi-value reduce-scatter: value bit3..0 <- lane bit5..2
#pragma unroll
    for (int v = 0; v < 8; ++v) {                     // stage xor 32
      double send = (lane & 32) ? p[v] : p[v+8];
      double recv = __shfl_xor(send, 32);
      double mine = (lane & 32) ? p[v+8] : p[v];
      p[v] = mine + recv;
    }
#pragma unroll
    for (int v = 0; v < 4; ++v) {                     // stage xor 16
      double send = (lane & 16) ? p[v] : p[v+4];
      double recv = __shfl_xor(send, 16);
      double mine = (lane & 16) ? p[v+4] : p[v];
      p[v] = mine + recv;
    }
#pragma unroll
    for (int v = 0; v < 2; ++v) {                     // stage xor 8
      double send = (lane & 8) ? p[v] : p[v+2];
      double recv = __shfl_xor(send, 8);
      double mine = (lane & 8) ? p[v+2] : p[v];
      p[v] = mine + recv;
    }
    {                                                 // stage xor 4
      double send = (lane & 4) ? p[0] : p[1];
      double recv = __shfl_xor(send, 4);
      double mine = (lane & 4) ? p[1] : p[0];
      p[0] = mine + recv;
    }
    p[0] += __shfl_xor(p[0], 2);                      // stage xor 2
    p[0] += __shfl_xor(p[0], 1);                      // stage xor 1

    const int v = ((lane >> 2) & 1) | (((lane >> 3) & 1) << 1)
                | (((lane >> 4) & 1) << 2) | (((lane >> 5) & 1) << 3);
    const int d = v + 1;
    if ((lane & 3) == 0 && i + d < seq_len) {
      const double s  = p[0] / (ni * (sqrt(ssq[cl + d]) + 1e-8));
      const double Ev = exp(5.0 * s);
      E[(size_t)i * 33 + 16 + d]       = Ev;
      E[(size_t)(i + d) * 33 + 16 - d] = Ev;
    }
  }
}

// ---- per-row sum of squares (f64) + d_out zeroing (FALLBACK path only) -----
__global__ __launch_bounds__(256) void rowsq_kernel(
    const float* __restrict__ H, double* __restrict__ sumsq,
    int* __restrict__ out, int out_n, int seq_len) {
  if (blockIdx.x == 0) {
    for (int t = threadIdx.x; t < out_n; t += 256) out[t] = 0;
  }
  const int row  = (int)((blockIdx.x * blockDim.x + threadIdx.x) >> 6);
  const int lane = threadIdx.x & 63;
  if (row >= seq_len) return;
  const float4* r = (const float4*)(H + (size_t)row * HID);
  double acc = 0.0;
#pragma unroll
  for (int k = 0; k < 4; ++k) {
    float4 x = r[lane + (k << 6)];
    acc += (double)x.x * x.x + (double)x.y * x.y
         + (double)x.z * x.z + (double)x.w * x.w;
  }
#pragma unroll
  for (int off = 32; off; off >>= 1) acc += __shfl_xor(acc, off);
  if (lane == 0) sumsq[row] = acc;
}

// ---- walk kernel: table-driven, E/w argmax, SALU key chain -----------------
__global__ __launch_bounds__(256) void walk_fast_kernel(
    const double* __restrict__ E, const double* __restrict__ sumsq,
    const int* __restrict__ viol, int* __restrict__ out,
    int nv, int seq_len) {
  int wave = (int)((blockIdx.x * blockDim.x + threadIdx.x) >> 6);
  const int lane = threadIdx.x & 63;
  if (wave >= nv * NUM_WALKS) return;
  wave = __builtin_amdgcn_readfirstlane(wave);
  const int v     = wave / NUM_WALKS;
  const int start = viol[v];

  uint32_t key0 = 0u, key1 = (uint32_t)wave;
  tf2x32(0u, 42u, key0, key1);
  key0 = __builtin_amdgcn_readfirstlane(key0);
  key1 = __builtin_amdgcn_readfirstlane(key1);

  int    cur = start, prev = start, plen = 1;
  double minE = 1e300;
  bool   detected = false;
  int    aborts = 0, restarts = 0;

  for (int step = 0; step < WALK_LEN; ++step) {
    // key, k_samp = split(key,3) -- scalar (SALU) chains; k_restart deferred
    uint32_t nk0 = 0u, nk1 = 0u; tf2x32(key0, key1, nk0, nk1);
    uint32_t ks0 = 0u, ks1 = 1u; tf2x32(key0, key1, ks0, ks1);

    const int  myidx   = cur - HALF_WIN + lane;
    const bool myvalid = (lane < 33) && (lane != HALF_WIN) &&
                         (myidx >= 0) && (myidx < seq_len);
    const double Ej = E[(size_t)cur * 33 + (lane < 33 ? lane : 0)];

    bool found = false; int fails = 0, p = 0, cand = 0;
    for (int at = 0; at < 3; ++at) {
      uint32_t s0 = 0u, s1 = (uint32_t)at; tf2x32(ks0, ks1, s0, s1);
      double f;
      if (myvalid) {
        const uint32_t bits = tf_fold(s0, s1, 0u, (uint32_t)lane);
        const uint32_t fb   = (bits >> 9) | 0x3f800000u;
        const float    ff   = __uint_as_float(fb) - 1.0f;
        const float    u    = (ff > 0.0f) ? ff : 1.1754943508222875e-38f;
        const double   w    = -log((double)u);        // w > 0
        f = Ej / w;           // argmax(E/w) == argmax(5*sim + gumbel)
      } else { f = -1.0; }
      // max butterfly (fmax returns an input exactly) + ballot + ffs:
      // lowest set lane == lowest index == old tie-break. Bit-identical pick.
      double m = f;
#pragma unroll
      for (int off = 32; off; off >>= 1) m = fmax(m, __shfl_xor(m, off));
      p    = (int)(__ffsll((unsigned long long)__ballot(f == m)) - 1);
      cand = cur - HALF_WIN + p;
      bool ok;
      if (plen < 2) ok = true;
      else {
        const float na = (float)sumsq[prev], nb = (float)sumsq[cur],
                    nc = (float)sumsq[cand];
        const float tr  = (na * nb * nc) /
                          ((na + 1e-8f) * (nb + 1e-8f) * (nc + 1e-8f));
        const float dev = fabsf(tr - rintf(tr));
        ok = (dev <= 0.1f) && (tr <= 1.5f);
      }
      if (ok) { found = true; break; }
      ++fails;
    }
    aborts += fails;

    if (found) {
      const double Ewin = __shfl(Ej, p);
      minE = fmin(minE, Ewin);
      const bool closed = (cand == start) && (plen > 2);
      prev = cur; cur = cand; plen += 1;
      if (closed) { if (minE < E_THRESH) detected = true; break; }
    } else {
      ++restarts;
      // k_restart chain only computed on the (rare) restart path;
      // key0/key1 still hold this step's key here.
      uint32_t kr0 = 0u, kr1 = 2u; tf2x32(key0, key1, kr0, kr1);
      uint32_t h0 = 0u, h1 = 0u; tf2x32(kr0, kr1, h0, h1);
      uint32_t l0 = 0u, l1 = 1u; tf2x32(kr0, kr1, l0, l1);
      const uint32_t hi = tf_fold(h0, h1, 0u, 0u);
      const uint32_t lo = tf_fold(l0, l1, 0u, 0u);
      const uint32_t span = (uint32_t)nv;
      uint32_t mult = (65536u % span); mult = (mult * mult) % span;
      const uint32_t r = ((hi % span) * mult + (lo % span)) % span;
      const int node = viol[r];
      cur = node; prev = node; plen = 1;
    }
    key0 = __builtin_amdgcn_readfirstlane(nk0);
    key1 = __builtin_amdgcn_readfirstlane(nk1);
  }

  if (lane == 0) {
    if (detected)      atomicOr(&out[v], 1);
    if (aborts != 0)   atomicAdd(&out[nv], aborts);
    if (restarts != 0) atomicAdd(&out[nv + 1], restarts);
  }
}

// ---- fallback: round-1 in-walk dot kernel (only if ws too small) -----------
__global__ __launch_bounds__(256) void walk_ref_kernel(
    const float* __restrict__ H, const int* __restrict__ viol,
    const double* __restrict__ sumsq, int* __restrict__ out,
    int nv, int seq_len) {
  const int wave = (int)((blockIdx.x * blockDim.x + threadIdx.x) >> 6);
  const int lane = threadIdx.x & 63;
  if (wave >= nv * NUM_WALKS) return;
  const int v     = wave / NUM_WALKS;
  const int start = viol[v];
  uint32_t key0 = 0u, key1 = (uint32_t)wave;
  tf2x32(0u, 42u, key0, key1);
  const float4* __restrict__ H4 = (const float4*)H;
  int    cur = start, prev = start, plen = 1;
  double min_sim = 1e9;
  bool   detected = false;
  int    aborts = 0, restarts = 0;
  for (int step = 0; step < WALK_LEN; ++step) {
    uint32_t nk0 = 0u, nk1 = 0u; tf2x32(key0, key1, nk0, nk1);
    uint32_t ks0 = 0u, ks1 = 1u; tf2x32(key0, key1, ks0, ks1);
    uint32_t kr0 = 0u, kr1 = 2u; tf2x32(key0, key1, kr0, kr1);
    const double ncur = sqrt(sumsq[cur]) + 1e-8;
    double a[16];
    {
      const float4* rc = H4 + ((size_t)cur << 8);
#pragma unroll
      for (int k = 0; k < 4; ++k) {
        float4 x = rc[lane + (k << 6)];
        a[4*k+0] = x.x; a[4*k+1] = x.y; a[4*k+2] = x.z; a[4*k+3] = x.w;
      }
    }
    double my_sim = 0.0;
    for (int j = 0; j < 33; ++j) {
      const int idx = cur - HALF_WIN + j;
      if (j == HALF_WIN || idx < 0 || idx >= seq_len) continue;
      const float4* rb = H4 + ((size_t)idx << 8);
      double acc = 0.0;
#pragma unroll
      for (int k = 0; k < 4; ++k) {
        float4 x = rb[lane + (k << 6)];
        acc += a[4*k+0] * (double)x.x + a[4*k+1] * (double)x.y
             + a[4*k+2] * (double)x.z + a[4*k+3] * (double)x.w;
      }
#pragma unroll
      for (int off = 32; off; off >>= 1) acc += __shfl_xor(acc, off);
      const double s = acc / (ncur * (sqrt(sumsq[idx]) + 1e-8));
      if (lane == j) my_sim = s;
    }
    bool found = false; int fails = 0, p = 0, cand = 0;
    const int  myidx   = cur - HALF_WIN + lane;
    const bool myvalid = (lane < 33) && (lane != HALF_WIN) &&
                         (myidx >= 0) && (myidx < seq_len);
    for (int at = 0; at < 3; ++at) {
      uint32_t s0 = 0u, s1 = (uint32_t)at; tf2x32(ks0, ks1, s0, s1);
      double z; int bi;
      if (myvalid) {
        const uint32_t bits = tf_fold(s0, s1, 0u, (uint32_t)lane);
        const uint32_t fb   = (bits >> 9) | 0x3f800000u;
        const float    f    = __uint_as_float(fb) - 1.0f;
        const float    u    = (f > 0.0f) ? f : 1.1754943508222875e-38f;
        const double   g    = -log(-log((double)u));
        z  = g + 5.0 * my_sim;
        bi = lane;
      } else { z = -1e300; bi = 1000; }
#pragma unroll
      for (int off = 32; off; off >>= 1) {
        const double oz = __shfl_xor(z, off);
        const int    oi = __shfl_xor(bi, off);
        if (oz > z || (oz == z && oi < bi)) { z = oz; bi = oi; }
      }
      p    = bi;
      cand = cur - HALF_WIN + p;
      bool ok;
      if (plen < 2) ok = true;
      else {
        const float na = (float)sumsq[prev], nb = (float)sumsq[cur],
                    nc = (float)sumsq[cand];
        const float tr  = (na * nb * nc) /
                          ((na + 1e-8f) * (nb + 1e-8f) * (nc + 1e-8f));
        const float dev = fabsf(tr - rintf(tr));
        ok = (dev <= 0.1f) && (tr <= 1.5f);
      }
      if (ok) { found = true; break; }
      ++fails;
    }
    aborts += fails;
    if (found) {
      const double sim = __shfl(my_sim, p);
      const double nm  = fmin(min_sim, sim);
      const bool closed = (cand == start) && (plen > 2);
      prev = cur; cur = cand; plen += 1; min_sim = nm;
      if (closed) { if (nm < 0.1) detected = true; break; }
    } else {
      ++restarts;
      uint32_t h0 = 0u, h1 = 0u; tf2x32(kr0, kr1, h0, h1);
      uint32_t l0 = 0u, l1 = 1u; tf2x32(kr0, kr1, l0, l1);
      const uint32_t hi = tf_fold(h0, h1, 0u, 0u);
      const uint32_t lo = tf_fold(l0, l1, 0u, 0u);
      const uint32_t span = (uint32_t)nv;
      uint32_t mult = (65536u % span); mult = (mult * mult) % span;
      const uint32_t r = ((hi % span) * mult + (lo % span)) % span;
      const int node = viol[r];
      cur = node; prev = node; plen = 1;
    }
    key0 = nk0; key1 = nk1;
  }
  if (lane == 0) {
    if (detected)      atomicOr(&out[v], 1);
    if (aborts != 0)   atomicAdd(&out[nv], aborts);
    if (restarts != 0) atomicAdd(&out[nv + 1], restarts);
  }
}

extern "C" void kernel_launch(void* const* d_in, const int* in_sizes, int n_in,
                              void* d_out, int out_size, void* d_ws, size_t ws_size,
                              hipStream_t stream) {
  const float* H    = (const float*)d_in[0];
  const int*   viol = (const int*)d_in[1];
  const int    nv      = in_sizes[1];
  const int    seq_len = in_sizes[0] / HID;

  double* sumsq = (double*)d_ws;                       // seq_len * 8 B
  double* Etab  = (double*)((char*)d_ws + (size_t)seq_len * sizeof(double));
  const size_t need = (size_t)seq_len * sizeof(double)
                    + (size_t)seq_len * 33 * sizeof(double);

  const int nwalks  = nv * NUM_WALKS;
  const int wblocks = (nwalks + 3) / 4;

  if (ws_size >= need) {
    const int blocks = (seq_len + CENTERS - 1) / CENTERS;   // 512 @ 8192
    band_fused_kernel<<<blocks, 512, 0, stream>>>(H, sumsq, Etab,
                                                  (int*)d_out, out_size,
                                                  seq_len);
    walk_fast_kernel<<<wblocks, 256, 0, stream>>>(Etab, sumsq, viol,
                                                  (int*)d_out, nv, seq_len);
  } else {
    const int blocks = (seq_len + 3) / 4;
    rowsq_kernel<<<blocks, 256, 0, stream>>>(H, sumsq, (int*)d_out,
                                             out_size, seq_len);
    walk_ref_kernel<<<wblocks, 256, 0, stream>>>(H, viol, sumsq,
                                                 (int*)d_out, nv, seq_len);
  }
}

// Round 2
// 68.105 us; speedup vs baseline: 1.2417x; 1.2417x over previous
//
#include <hip/hip_runtime.h>
#include <stdint.h>
#include <math.h>

// ---------------------------------------------------------------------------
// SparseExplorerRouting, round 5.
//
// Carried facts (R1-R3 PASSED, absmax 0; R4 passed but regressed):
//   * jax_threefry_partitionable=True counter scheme; key(42) -> (0,42);
//     walk (v,w) = split child v*5+w; per-step children ctr (0,{0,1,2}).
//   * output int32 {flags[1024], sum_aborts, sum_restarts}.
//   * f64 analog math proxy for the f32 reference passes with margin.
//   * E-table argmax(E/w) trick, w=-log(u); minE<e^0.5 == min_sim<0.1.
//   * R4 lesson: walk is latency-chain bound; ballot-argmax + in-branch kr
//     chains REGRESSED it 42->54us (SGPR 64->112). Reverted to R3 body.
//   * R4 lesson: band was scratch-bound, not L2-bound: p[d-1] with runtime
//     dmax forced p[16] into scratch (rule: runtime-indexed locals spill).
//
// Round 5 changes:
//   * band: d-loop fully unrolled 1..16 (static p[] indices -> registers).
//     d<=dmax <=> i+d<seq_len is exactly the existing write guard; halo-row
//     garbage partials stay segregated per-d through the reduce-scatter and
//     never reach an unguarded write. Bit-identical E.
//   * walk: exact R3 body + per-lane sumsq window preload; nc for the cycle
//     check comes from __shfl(sq_win, p) instead of a pick-dependent global
//     load; na/nb carried in registers across steps. Bit-identical values.
// ---------------------------------------------------------------------------

#define HID        1024
#define NUM_WALKS  5
#define WALK_LEN   8
#define HALF_WIN   16
#define E_THRESH   1.6487212707001282   // exp(0.5) = exp(5 * BIRTH_DEATH_EPS)

#define CENTERS    16                   // centers per band block
#define SROWS      32                   // staged rows = CENTERS + 16 halo

__device__ __forceinline__ void tf2x32(uint32_t k0, uint32_t k1,
                                       uint32_t& x0, uint32_t& x1) {
  uint32_t ks2 = k0 ^ k1 ^ 0x1BD11BDAu;
  x0 += k0; x1 += k1;
#define TFR(r) { x0 += x1; x1 = (x1 << (r)) | (x1 >> (32 - (r))); x1 ^= x0; }
  TFR(13) TFR(15) TFR(26) TFR(6)
  x0 += k1;  x1 += ks2 + 1u;
  TFR(17) TFR(29) TFR(16) TFR(24)
  x0 += ks2; x1 += k0 + 2u;
  TFR(13) TFR(15) TFR(26) TFR(6)
  x0 += k0;  x1 += k1 + 3u;
  TFR(17) TFR(29) TFR(16) TFR(24)
  x0 += k1;  x1 += ks2 + 4u;
  TFR(13) TFR(15) TFR(26) TFR(6)
  x0 += ks2; x1 += k0 + 5u;
#undef TFR
}

__device__ __forceinline__ uint32_t tf_fold(uint32_t k0, uint32_t k1,
                                            uint32_t c0, uint32_t c1) {
  tf2x32(k0, k1, c0, c1);
  return c0 ^ c1;
}

// ---- fused band + rowsq + d_out zeroing ------------------------------------
// Block = 512 threads (8 waves) = 16 centers. Stage rows [i0, i0+32) as f32
// in LDS; compute per-row sumsq during staging (bit-identical order to the
// old rowsq kernel); then 16 forward dots per center from LDS with the d-loop
// FULLY UNROLLED so p[] stays in registers. E[i][16+d]=E[i+d][16-d]=exp(5*sim).
__global__ __launch_bounds__(512) void band_fused_kernel(
    const float* __restrict__ H, double* __restrict__ sumsq,
    double* __restrict__ E, int* __restrict__ out, int out_n, int seq_len) {
  __shared__ __align__(16) float  tile[SROWS][HID];   // 128 KB
  __shared__ double ssq[SROWS];

  if (blockIdx.x == 0) {                 // fold d_out zeroing in (dispatch
    for (int t = threadIdx.x; t < out_n; t += 512) out[t] = 0;   // ordering
  }                                      // guarantees walk sees zeros)

  int wg = blockIdx.x;
  {
    const int nwg = gridDim.x;           // bijective XCD swizzle (nwg%8==0)
    if ((nwg & 7) == 0) wg = (wg & 7) * (nwg >> 3) + (wg >> 3);
  }
  const int wid  = (int)(threadIdx.x >> 6);   // 0..7
  const int lane = (int)(threadIdx.x & 63);
  const int i0   = wg * CENTERS;
  const float4* __restrict__ H4 = (const float4*)H;

  // ---- stage 4 rows per wave + sumsq (same order as old rowsq) ----
#pragma unroll
  for (int rr = 0; rr < 4; ++rr) {
    const int local = wid * 4 + rr;      // wave-uniform
    const int row   = i0 + local;
    if (row < seq_len) {
      const float4* src = H4 + ((size_t)row << 8);
      float4* dst = (float4*)&tile[local][0];
      double acc = 0.0;
#pragma unroll
      for (int k = 0; k < 4; ++k) {
        float4 x = src[lane + (k << 6)];
        dst[lane + (k << 6)] = x;
        acc += (double)x.x * x.x + (double)x.y * x.y
             + (double)x.z * x.z + (double)x.w * x.w;
      }
#pragma unroll
      for (int off = 32; off; off >>= 1) acc += __shfl_xor(acc, off);
      if (lane == 0) {
        ssq[local] = acc;
        if (local < CENTERS) sumsq[row] = acc;   // each row owned by 1 block
      }
    }
  }
  __syncthreads();

  // ---- 2 centers per wave, 16 forward dots each, from LDS ----
#pragma unroll
  for (int cc = 0; cc < 2; ++cc) {
    const int cl = wid * 2 + cc;         // 0..15, wave-uniform
    const int i  = i0 + cl;
    if (i >= seq_len) continue;

    double a[16];
    {
      const float4* rc = (const float4*)&tile[cl][0];
#pragma unroll
      for (int k = 0; k < 4; ++k) {
        float4 x = rc[lane + (k << 6)];
        a[4*k+0] = x.x; a[4*k+1] = x.y; a[4*k+2] = x.z; a[4*k+3] = x.w;
      }
    }
    const double ni = sqrt(ssq[cl]) + 1e-8;

    // d-loop fully unrolled: p[] indices static -> registers, no scratch.
    // For d where i+d >= seq_len the partials are garbage from unstaged
    // LDS rows (reads stay inside tile[0..31]); the reduce-scatter keeps
    // per-d values segregated and the output write below is guarded by
    // i+d < seq_len (== the old d<=dmax bound). Bit-identical valid E.
    double p[16];
#pragma unroll
    for (int d = 0; d < 16; ++d) p[d] = 0.0;
#pragma unroll
    for (int d = 1; d <= 16; ++d) {
      const float4* rb = (const float4*)&tile[cl + d][0];
#pragma unroll
      for (int k = 0; k < 4; ++k) {
        float4 x = rb[lane + (k << 6)];
        p[d-1] += a[4*k+0] * (double)x.x + a[4*k+1] * (double)x.y
                + a[4*k+2] * (double)x.z + a[4*k+3] * (double)x.w;
      }
    }

    // multi-value reduce-scatter: value bit3..0 <- lane bit5..2
#pragma unroll
    for (int v = 0; v < 8; ++v) {                     // stage xor 32
      double send = (lane & 32) ? p[v] : p[v+8];
      double recv = __shfl_xor(send, 32);
      double mine = (lane & 32) ? p[v+8] : p[v];
      p[v] = mine + recv;
    }
#pragma unroll
    for (int v = 0; v < 4; ++v) {                     // stage xor 16
      double send = (lane & 16) ? p[v] : p[v+4];
      double recv = __shfl_xor(send, 16);
      double mine = (lane & 16) ? p[v+4] : p[v];
      p[v] = mine + recv;
    }
#pragma unroll
    for (int v = 0; v < 2; ++v) {                     // stage xor 8
      double send = (lane & 8) ? p[v] : p[v+2];
      double recv = __shfl_xor(send, 8);
      double mine = (lane & 8) ? p[v+2] : p[v];
      p[v] = mine + recv;
    }
    {                                                 // stage xor 4
      double send = (lane & 4) ? p[0] : p[1];
      double recv = __shfl_xor(send, 4);
      double mine = (lane & 4) ? p[1] : p[0];
      p[0] = mine + recv;
    }
    p[0] += __shfl_xor(p[0], 2);                      // stage xor 2
    p[0] += __shfl_xor(p[0], 1);                      // stage xor 1

    const int v = ((lane >> 2) & 1) | (((lane >> 3) & 1) << 1)
                | (((lane >> 4) & 1) << 2) | (((lane >> 5) & 1) << 3);
    const int d = v + 1;
    if ((lane & 3) == 0 && i + d < seq_len) {
      const double s  = p[0] / (ni * (sqrt(ssq[cl + d]) + 1e-8));
      const double Ev = exp(5.0 * s);
      E[(size_t)i * 33 + 16 + d]       = Ev;
      E[(size_t)(i + d) * 33 + 16 - d] = Ev;
    }
  }
}

// ---- per-row sum of squares (f64) + d_out zeroing (FALLBACK path only) -----
__global__ __launch_bounds__(256) void rowsq_kernel(
    const float* __restrict__ H, double* __restrict__ sumsq,
    int* __restrict__ out, int out_n, int seq_len) {
  if (blockIdx.x == 0) {
    for (int t = threadIdx.x; t < out_n; t += 256) out[t] = 0;
  }
  const int row  = (int)((blockIdx.x * blockDim.x + threadIdx.x) >> 6);
  const int lane = threadIdx.x & 63;
  if (row >= seq_len) return;
  const float4* r = (const float4*)(H + (size_t)row * HID);
  double acc = 0.0;
#pragma unroll
  for (int k = 0; k < 4; ++k) {
    float4 x = r[lane + (k << 6)];
    acc += (double)x.x * x.x + (double)x.y * x.y
         + (double)x.z * x.z + (double)x.w * x.w;
  }
#pragma unroll
  for (int off = 32; off; off >>= 1) acc += __shfl_xor(acc, off);
  if (lane == 0) sumsq[row] = acc;
}

// ---- walk kernel: R3 body + sumsq-window preload ---------------------------
__global__ __launch_bounds__(256) void walk_fast_kernel(
    const double* __restrict__ E, const double* __restrict__ sumsq,
    const int* __restrict__ viol, int* __restrict__ out,
    int nv, int seq_len) {
  int wave = (int)((blockIdx.x * blockDim.x + threadIdx.x) >> 6);
  const int lane = threadIdx.x & 63;
  if (wave >= nv * NUM_WALKS) return;
  wave = __builtin_amdgcn_readfirstlane(wave);
  const int v     = wave / NUM_WALKS;
  const int start = viol[v];

  uint32_t key0 = 0u, key1 = (uint32_t)wave;
  tf2x32(0u, 42u, key0, key1);
  key0 = __builtin_amdgcn_readfirstlane(key0);
  key1 = __builtin_amdgcn_readfirstlane(key1);

  int    cur = start, prev = start, plen = 1;
  double minE = 1e300;
  bool   detected = false;
  int    aborts = 0, restarts = 0;
  // carried |h|^2 of prev / cur (identical doubles to sumsq[] entries)
  double na_d = sumsq[start], nb_d = na_d;

  for (int step = 0; step < WALK_LEN; ++step) {
    // key, k_samp, k_restart = split(key,3) -- scalar (SALU) chain
    uint32_t nk0 = 0u, nk1 = 0u; tf2x32(key0, key1, nk0, nk1);
    uint32_t ks0 = 0u, ks1 = 1u; tf2x32(key0, key1, ks0, ks1);
    uint32_t kr0 = 0u, kr1 = 2u; tf2x32(key0, key1, kr0, kr1);

    const int  myidx   = cur - HALF_WIN + lane;
    const bool myvalid = (lane < 33) && (lane != HALF_WIN) &&
                         (myidx >= 0) && (myidx < seq_len);
    const int  clipped = myidx < 0 ? 0 : (myidx >= seq_len ? seq_len - 1 : myidx);
    const double Ej = E[(size_t)cur * 33 + (lane < 33 ? lane : 0)];
    const double sq_win = sumsq[clipped];   // window |h|^2, issued with Ej

    bool found = false; int fails = 0, p = 0, cand = 0;
    double nc_d = 0.0;
    for (int at = 0; at < 3; ++at) {
      uint32_t s0 = 0u, s1 = (uint32_t)at; tf2x32(ks0, ks1, s0, s1);
      double f; int bi;
      if (myvalid) {
        const uint32_t bits = tf_fold(s0, s1, 0u, (uint32_t)lane);
        const uint32_t fb   = (bits >> 9) | 0x3f800000u;
        const float    ff   = __uint_as_float(fb) - 1.0f;
        const float    u    = (ff > 0.0f) ? ff : 1.1754943508222875e-38f;
        const double   w    = -log((double)u);        // w > 0
        f  = Ej / w;          // argmax(E/w) == argmax(5*sim + gumbel)
        bi = lane;
      } else { f = -1.0; bi = 1000; }
#pragma unroll
      for (int off = 32; off; off >>= 1) {
        const double of = __shfl_xor(f, off);
        const int    oi = __shfl_xor(bi, off);
        if (of > f || (of == f && oi < bi)) { f = of; bi = oi; }
      }
      p    = bi;
      cand = cur - HALF_WIN + p;
      nc_d = __shfl(sq_win, p);     // == sumsq[cand], no dependent load
      bool ok;
      if (plen < 2) ok = true;
      else {
        const float na = (float)na_d, nb = (float)nb_d, nc = (float)nc_d;
        const float tr  = (na * nb * nc) /
                          ((na + 1e-8f) * (nb + 1e-8f) * (nc + 1e-8f));
        const float dev = fabsf(tr - rintf(tr));
        ok = (dev <= 0.1f) && (tr <= 1.5f);
      }
      if (ok) { found = true; break; }
      ++fails;
    }
    aborts += fails;

    if (found) {
      const double Ewin = __shfl(Ej, p);
      minE = fmin(minE, Ewin);
      const bool closed = (cand == start) && (plen > 2);
      prev = cur; cur = cand; plen += 1;
      na_d = nb_d; nb_d = nc_d;
      if (closed) { if (minE < E_THRESH) detected = true; break; }
    } else {
      ++restarts;
      uint32_t h0 = 0u, h1 = 0u; tf2x32(kr0, kr1, h0, h1);
      uint32_t l0 = 0u, l1 = 1u; tf2x32(kr0, kr1, l0, l1);
      const uint32_t hi = tf_fold(h0, h1, 0u, 0u);
      const uint32_t lo = tf_fold(l0, l1, 0u, 0u);
      const uint32_t span = (uint32_t)nv;
      uint32_t mult = (65536u % span); mult = (mult * mult) % span;
      const uint32_t r = ((hi % span) * mult + (lo % span)) % span;
      const int node = viol[r];
      cur = node; prev = node; plen = 1;
      na_d = sumsq[node]; nb_d = na_d;   // rare path, load tolerated
    }
    key0 = __builtin_amdgcn_readfirstlane(nk0);
    key1 = __builtin_amdgcn_readfirstlane(nk1);
  }

  if (lane == 0) {
    if (detected)      atomicOr(&out[v], 1);
    if (aborts != 0)   atomicAdd(&out[nv], aborts);
    if (restarts != 0) atomicAdd(&out[nv + 1], restarts);
  }
}

// ---- fallback: round-1 in-walk dot kernel (only if ws too small) -----------
__global__ __launch_bounds__(256) void walk_ref_kernel(
    const float* __restrict__ H, const int* __restrict__ viol,
    const double* __restrict__ sumsq, int* __restrict__ out,
    int nv, int seq_len) {
  const int wave = (int)((blockIdx.x * blockDim.x + threadIdx.x) >> 6);
  const int lane = threadIdx.x & 63;
  if (wave >= nv * NUM_WALKS) return;
  const int v     = wave / NUM_WALKS;
  const int start = viol[v];
  uint32_t key0 = 0u, key1 = (uint32_t)wave;
  tf2x32(0u, 42u, key0, key1);
  const float4* __restrict__ H4 = (const float4*)H;
  int    cur = start, prev = start, plen = 1;
  double min_sim = 1e9;
  bool   detected = false;
  int    aborts = 0, restarts = 0;
  for (int step = 0; step < WALK_LEN; ++step) {
    uint32_t nk0 = 0u, nk1 = 0u; tf2x32(key0, key1, nk0, nk1);
    uint32_t ks0 = 0u, ks1 = 1u; tf2x32(key0, key1, ks0, ks1);
    uint32_t kr0 = 0u, kr1 = 2u; tf2x32(key0, key1, kr0, kr1);
    const double ncur = sqrt(sumsq[cur]) + 1e-8;
    double a[16];
    {
      const float4* rc = H4 + ((size_t)cur << 8);
#pragma unroll
      for (int k = 0; k < 4; ++k) {
        float4 x = rc[lane + (k << 6)];
        a[4*k+0] = x.x; a[4*k+1] = x.y; a[4*k+2] = x.z; a[4*k+3] = x.w;
      }
    }
    double my_sim = 0.0;
    for (int j = 0; j < 33; ++j) {
      const int idx = cur - HALF_WIN + j;
      if (j == HALF_WIN || idx < 0 || idx >= seq_len) continue;
      const float4* rb = H4 + ((size_t)idx << 8);
      double acc = 0.0;
#pragma unroll
      for (int k = 0; k < 4; ++k) {
        float4 x = rb[lane + (k << 6)];
        acc += a[4*k+0] * (double)x.x + a[4*k+1] * (double)x.y
             + a[4*k+2] * (double)x.z + a[4*k+3] * (double)x.w;
      }
#pragma unroll
      for (int off = 32; off; off >>= 1) acc += __shfl_xor(acc, off);
      const double s = acc / (ncur * (sqrt(sumsq[idx]) + 1e-8));
      if (lane == j) my_sim = s;
    }
    bool found = false; int fails = 0, p = 0, cand = 0;
    const int  myidx   = cur - HALF_WIN + lane;
    const bool myvalid = (lane < 33) && (lane != HALF_WIN) &&
                         (myidx >= 0) && (myidx < seq_len);
    for (int at = 0; at < 3; ++at) {
      uint32_t s0 = 0u, s1 = (uint32_t)at; tf2x32(ks0, ks1, s0, s1);
      double z; int bi;
      if (myvalid) {
        const uint32_t bits = tf_fold(s0, s1, 0u, (uint32_t)lane);
        const uint32_t fb   = (bits >> 9) | 0x3f800000u;
        const float    f    = __uint_as_float(fb) - 1.0f;
        const float    u    = (f > 0.0f) ? f : 1.1754943508222875e-38f;
        const double   g    = -log(-log((double)u));
        z  = g + 5.0 * my_sim;
        bi = lane;
      } else { z = -1e300; bi = 1000; }
#pragma unroll
      for (int off = 32; off; off >>= 1) {
        const double oz = __shfl_xor(z, off);
        const int    oi = __shfl_xor(bi, off);
        if (oz > z || (oz == z && oi < bi)) { z = oz; bi = oi; }
      }
      p    = bi;
      cand = cur - HALF_WIN + p;
      bool ok;
      if (plen < 2) ok = true;
      else {
        const float na = (float)sumsq[prev], nb = (float)sumsq[cur],
                    nc = (float)sumsq[cand];
        const float tr  = (na * nb * nc) /
                          ((na + 1e-8f) * (nb + 1e-8f) * (nc + 1e-8f));
        const float dev = fabsf(tr - rintf(tr));
        ok = (dev <= 0.1f) && (tr <= 1.5f);
      }
      if (ok) { found = true; break; }
      ++fails;
    }
    aborts += fails;
    if (found) {
      const double sim = __shfl(my_sim, p);
      const double nm  = fmin(min_sim, sim);
      const bool closed = (cand == start) && (plen > 2);
      prev = cur; cur = cand; plen += 1; min_sim = nm;
      if (closed) { if (nm < 0.1) detected = true; break; }
    } else {
      ++restarts;
      uint32_t h0 = 0u, h1 = 0u; tf2x32(kr0, kr1, h0, h1);
      uint32_t l0 = 0u, l1 = 1u; tf2x32(kr0, kr1, l0, l1);
      const uint32_t hi = tf_fold(h0, h1, 0u, 0u);
      const uint32_t lo = tf_fold(l0, l1, 0u, 0u);
      const uint32_t span = (uint32_t)nv;
      uint32_t mult = (65536u % span); mult = (mult * mult) % span;
      const uint32_t r = ((hi % span) * mult + (lo % span)) % span;
      const int node = viol[r];
      cur = node; prev = node; plen = 1;
    }
    key0 = nk0; key1 = nk1;
  }
  if (lane == 0) {
    if (detected)      atomicOr(&out[v], 1);
    if (aborts != 0)   atomicAdd(&out[nv], aborts);
    if (restarts != 0) atomicAdd(&out[nv + 1], restarts);
  }
}

extern "C" void kernel_launch(void* const* d_in, const int* in_sizes, int n_in,
                              void* d_out, int out_size, void* d_ws, size_t ws_size,
                              hipStream_t stream) {
  const float* H    = (const float*)d_in[0];
  const int*   viol = (const int*)d_in[1];
  const int    nv      = in_sizes[1];
  const int    seq_len = in_sizes[0] / HID;

  double* sumsq = (double*)d_ws;                       // seq_len * 8 B
  double* Etab  = (double*)((char*)d_ws + (size_t)seq_len * sizeof(double));
  const size_t need = (size_t)seq_len * sizeof(double)
                    + (size_t)seq_len * 33 * sizeof(double);

  const int nwalks  = nv * NUM_WALKS;
  const int wblocks = (nwalks + 3) / 4;

  if (ws_size >= need) {
    const int blocks = (seq_len + CENTERS - 1) / CENTERS;   // 512 @ 8192
    band_fused_kernel<<<blocks, 512, 0, stream>>>(H, sumsq, Etab,
                                                  (int*)d_out, out_size,
                                                  seq_len);
    walk_fast_kernel<<<wblocks, 256, 0, stream>>>(Etab, sumsq, viol,
                                                  (int*)d_out, nv, seq_len);
  } else {
    const int blocks = (seq_len + 3) / 4;
    rowsq_kernel<<<blocks, 256, 0, stream>>>(H, sumsq, (int*)d_out,
                                             out_size, seq_len);
    walk_ref_kernel<<<wblocks, 256, 0, stream>>>(H, viol, sumsq,
                                                 (int*)d_out, nv, seq_len);
  }
}